// Round 6
// baseline (672.177 us; speedup 1.0000x reference)
//
#include <hip/hip_runtime.h>

// NeuralAudioGraph: N=256, D=H=512, E=128, 4 heads, 3 GAT layers.
// r6 KEY FIX: outputs are FLOAT32 ("else float*" — reference returns f32).
// Rounds 2-5 wrote bf16 u16 into the f32 buffer; the bit-identical 1.611 error
// was our unchanged k_ef bf16 words composed pairwise into f32 reads.
// Pipeline: literal f64 edge predictor, naive-f32 tiled edge features,
// naive f32 GAT chain. All correctness-first; optimize once green.

typedef unsigned short u16;
typedef unsigned int u32;

__device__ __forceinline__ float bf2f(u16 h) { return __uint_as_float(((u32)h) << 16); }
__device__ __forceinline__ float lrelu(float v) { return fmaxf(v, 0.2f * v); }
__device__ __forceinline__ float ldany(int f32mode, const void* p, int i) {
  return f32mode ? ((const float*)p)[i] : bf2f(((const u16*)p)[i]);
}

// ---------------- dtype detector: f32 bits read as bf16 contain huge values --------
__global__ __launch_bounds__(256) void k_detect(const u16* emb, int* flag) {
  bool big = false;
  for (int i = blockIdx.x * 256 + threadIdx.x; i < 131072; i += 256 * 64) {
    float v = bf2f(emb[i]);
    big |= !(fabsf(v) <= 1e6f);
  }
  unsigned long long m = __ballot(big);
  if (m && (threadIdx.x & 63) == 0) atomicOr(flag, 1);
}

// ---------------- small-vector ingest -> canonical f32 ------------------------------
struct VD { const void* src; int dst, n; };
struct VArgs { VD v[16]; };
__global__ __launch_bounds__(256) void k_vec(VArgs a, const int* flag, float* out) {
  int f = *flag;
  VD d = a.v[blockIdx.x];
  for (int i = threadIdx.x; i < d.n; i += 256)
    out[d.dst + i] = ldany(f, d.src, i);
}

// ---------------- big-matrix ingest -> canonical f32 --------------------------------
struct CArgs { const void* src[7]; float* dst[7]; int n[7]; };
__global__ __launch_bounds__(256) void k_cvt(CArgs a, const int* flag) {
  int f = *flag;
  int e = blockIdx.y;
  const void* s = a.src[e];
  float* d = a.dst[e];
  int n = a.n[e];
  for (int i = blockIdx.x * 256 + threadIdx.x; i < n; i += 2048 * 256)
    d[i] = ldany(f, s, i);
}

// ---------------- U/V = emb @ W1 halves, f64 accumulate, f32 out --------------------
// arr 0: U_ep, 1: V_ep(+ep_b1), 2: U_ef, 3: V_ef(+ef_b1)
__global__ __launch_bounds__(256) void k_uv(const float* embf, const float* epw1f,
    const float* efw1f, const float* vecf, float* uvf) {
  int idx = blockIdx.x * 256 + threadIdx.x;   // 524288
  int col = idx & 511;
  int row = (idx >> 9) & 255;
  int arr = idx >> 17;
  const float* W = (arr < 2) ? epw1f : efw1f;
  const float* e = embf + row * 512;
  const float* w = W + (arr & 1) * 512 * 512 + col;
  double acc = 0.0;
  for (int c = 0; c < 512; ++c)
    acc += (double)e[c] * (double)w[c * 512];
  float bias = (arr == 1) ? vecf[col] : (arr == 3) ? vecf[2064 + col] : 0.f;
  uvf[idx] = (float)(acc + (double)bias);
}

// ---------------- f64 row sums / sums-of-squares (feeds k_efn) ----------------------
__global__ __launch_bounds__(64) void k_stats64(const float* uvf, double* sums, double* sumsq) {
  int bid = blockIdx.x;           // arr*256 + row
  int lane = threadIdx.x;
  const float* p = uvf + bid * 512;
  double s = 0.0, s2 = 0.0;
  for (int q = lane; q < 512; q += 64) { double v = p[q]; s += v; s2 += v * v; }
#pragma unroll
  for (int m = 1; m < 64; m <<= 1) { s += __shfl_xor(s, m, 64); s2 += __shfl_xor(s2, m, 64); }
  if (lane == 0) { sums[bid] = s; sumsq[bid] = s2; }
}

// ---------------- cross[i][j] = U_i . V_j (f64) for the ef LN variance --------------
__global__ __launch_bounds__(256) void k_cross(const float* uvf, double* crossef) {
  __shared__ float Uc[16][132], Vc[16][132];
  const float* U = uvf + 262144;
  const float* V = U + 131072;
  int tid = threadIdx.x, ti = tid & 15, tj = tid >> 4;
  int i0 = blockIdx.y * 16, j0 = blockIdx.x * 16;
  double acc = 0.0;
  for (int c0 = 0; c0 < 512; c0 += 128) {
    __syncthreads();
    for (int idx = tid; idx < 2048; idx += 256) {
      int r = idx >> 7, c = idx & 127;
      Uc[r][c] = U[(i0 + r) * 512 + c0 + c];
      Vc[r][c] = V[(j0 + r) * 512 + c0 + c];
    }
    __syncthreads();
    for (int c = 0; c < 128; ++c)
      acc += (double)Uc[ti][c] * (double)Vc[tj][c];
  }
  crossef[(i0 + ti) * 256 + j0 + tj] = acc;
}

// ---------------- LITERAL edge predictor: one wave per pair -------------------------
// active -> f32 0/1; maskv[dst][src] for GAT.
__global__ __launch_bounds__(256) void k_ep_lit(const float* uvf, const float* vecf,
                                                float* act, float* maskv) {
  int lane = threadIdx.x & 63, w = threadIdx.x >> 6;
  int pair = blockIdx.x * 4 + w;           // grid 16384
  int i = pair >> 8, j = pair & 255;
  const float* Up = uvf + i * 512 + lane * 8;
  const float* Vp = uvf + 131072 + j * 512 + lane * 8;
  float4 u0 = *(const float4*)Up, u1 = *(const float4*)(Up + 4);
  float4 v0 = *(const float4*)Vp, v1 = *(const float4*)(Vp + 4);
  float h[8] = {u0.x + v0.x, u0.y + v0.y, u0.z + v0.z, u0.w + v0.w,
                u1.x + v1.x, u1.y + v1.y, u1.z + v1.z, u1.w + v1.w};
  double s = 0.0;
#pragma unroll
  for (int k = 0; k < 8; ++k) s += (double)h[k];
#pragma unroll
  for (int m = 1; m < 64; m <<= 1) s += __shfl_xor(s, m, 64);
  float mean = (float)(s * (1.0 / 512.0));
  double q = 0.0;
#pragma unroll
  for (int k = 0; k < 8; ++k) { double dd = (double)(h[k] - mean); q += dd * dd; }
#pragma unroll
  for (int m = 1; m < 64; m <<= 1) q += __shfl_xor(q, m, 64);
  float iv = (float)(1.0 / sqrt(q * (1.0 / 512.0) + 1e-5));
  const float* g_ = vecf + 512 + lane * 8;
  const float* be_ = vecf + 1024 + lane * 8;
  const float* w2_ = vecf + 1536 + lane * 8;
  double acc = 0.0;
#pragma unroll
  for (int k = 0; k < 8; ++k) {
    float z = (h[k] - mean) * iv * g_[k] + be_[k];
    acc += (double)(lrelu(z) * w2_[k]);
  }
#pragma unroll
  for (int m = 1; m < 64; m <<= 1) acc += __shfl_xor(acc, m, 64);
  if (lane == 0) {
    double logit = acc + (double)vecf[2048];
    bool a = (logit > 0.0) && (i != j);
    act[i * 256 + j] = a ? 1.0f : 0.0f;
    maskv[j * 256 + i] = (a || i == j) ? 0.f : -1e9f;         // adj[dst][src] mask
  }
}

// ---------------- edge features, naive f32 tiled: 1 i x 32 j x 128 n per block ------
// h = leaky(LN(U_i+V_j)*g+beta) computed on the fly into LDS; full f32 accuracy.
__global__ __launch_bounds__(256) void k_efn(const float* uvf, const double* sums,
    const double* sumsq, const double* crossef, const float* vecf,
    const float* w2f, float* ef_f) {
  __shared__ float wS[32 * 128];    // [c][n]
  __shared__ float hS[32 * 36];     // [pp][c] padded
  __shared__ float ivI[32], bI[32];
  const float* g_ = vecf + 2576;
  const float* be_ = vecf + 3088;
  int tid = threadIdx.x;
  int bx = blockIdx.x;              // 2048
  int i0 = bx >> 3, j0 = (bx & 7) * 32;
  if (tid < 32) {
    int j = j0 + tid;
    double m = (sums[512 + i0] + sums[768 + j]) * (1.0 / 512.0);
    double q = (sumsq[512 + i0] + 2.0 * crossef[i0 * 256 + j] + sumsq[768 + j]) * (1.0 / 512.0);
    float iv = (float)(1.0 / sqrt(q - m * m + 1e-5));
    ivI[tid] = iv;
    bI[tid] = (float)(-m) * iv;
  }
  float acc[4][4];
#pragma unroll
  for (int a = 0; a < 4; ++a)
#pragma unroll
    for (int b = 0; b < 4; ++b) acc[a][b] = 0.f;
  __syncthreads();
  const float* U = uvf + 262144 + i0 * 512;
  const float* V = uvf + 393216 + (j0 + (tid >> 3)) * 512;
  int pp = tid >> 3, cz = (tid & 7) * 4;
  int n4 = (tid & 31) * 4, ph = (tid >> 5) * 4;
  for (int kc = 0; kc < 16; ++kc) {
    int c0 = kc * 32;
    if (kc) __syncthreads();
#pragma unroll
    for (int q = 0; q < 16; ++q) {            // stage ef_w2 chunk [32c][128n]
      int idx = q * 256 + tid;
      int c = idx >> 7, n = idx & 127;
      wS[c * 128 + n] = w2f[(c0 + c) * 128 + n];
    }
    {                                          // h chunk for pair pp, 4 channels
      float iv = ivI[pp], bb = bI[pp];
#pragma unroll
      for (int r = 0; r < 4; ++r) {
        int c = c0 + cz + r;
        float t = U[c] + V[c];
        float z = fmaf(t, iv, bb);
        z = fmaf(z, g_[c], be_[c]);
        hS[pp * 36 + cz + r] = lrelu(z);
      }
    }
    __syncthreads();
#pragma unroll
    for (int cg = 0; cg < 8; ++cg) {
      float4 w0 = *(const float4*)&wS[(cg * 4 + 0) * 128 + n4];
      float4 w1 = *(const float4*)&wS[(cg * 4 + 1) * 128 + n4];
      float4 w2 = *(const float4*)&wS[(cg * 4 + 2) * 128 + n4];
      float4 w3 = *(const float4*)&wS[(cg * 4 + 3) * 128 + n4];
#pragma unroll
      for (int qi = 0; qi < 4; ++qi) {
        float4 hv = *(const float4*)&hS[(ph + qi) * 36 + cg * 4];
        acc[qi][0] = fmaf(hv.x, w0.x, fmaf(hv.y, w1.x, fmaf(hv.z, w2.x, fmaf(hv.w, w3.x, acc[qi][0]))));
        acc[qi][1] = fmaf(hv.x, w0.y, fmaf(hv.y, w1.y, fmaf(hv.z, w2.y, fmaf(hv.w, w3.y, acc[qi][1]))));
        acc[qi][2] = fmaf(hv.x, w0.z, fmaf(hv.y, w1.z, fmaf(hv.z, w2.z, fmaf(hv.w, w3.z, acc[qi][2]))));
        acc[qi][3] = fmaf(hv.x, w0.w, fmaf(hv.y, w1.w, fmaf(hv.z, w2.w, fmaf(hv.w, w3.w, acc[qi][3]))));
      }
    }
  }
#pragma unroll
  for (int qi = 0; qi < 4; ++qi) {
    int pair = i0 * 256 + j0 + ph + qi;
#pragma unroll
    for (int nr = 0; nr < 4; ++nr)
      ef_f[pair * 128 + n4 + nr] = acc[qi][nr] + vecf[3600 + n4 + nr];
  }
}

// ---------------- naive GAT: s = x @ W[l]  (thread per (n,hc)) ----------------------
__global__ __launch_bounds__(256) void k_s(const float* x, const float* Wf, float* sf) {
  int hc = blockIdx.x * 256 + threadIdx.x;   // grid.x = 8
  int n = blockIdx.y;
  const float* xr = x + n * 512;
  const float* w = Wf + hc;
  float acc = 0.f;
  for (int c = 0; c < 512; ++c) acc = fmaf(xr[c], w[c * 2048], acc);
  sf[n * 2048 + hc] = acc;
}

// ---------------- naive a_src/a_dst dots (block per (n,h)) --------------------------
__global__ __launch_bounds__(64) void k_ad(const float* sf, const float* vecf, int l,
                                           float* asf, float* adf) {
  int b = blockIdx.x;            // n*4+h
  int n = b >> 2, h = b & 3;
  int lane = threadIdx.x;
  const float* s = sf + n * 2048 + h * 512;
  const float* as_ = vecf + 3728 + l * 2048 + h * 512;
  const float* ad_ = vecf + 9872 + l * 2048 + h * 512;
  float sa = 0.f, sd = 0.f;
  for (int c = lane; c < 512; c += 64) { sa = fmaf(s[c], as_[c], sa); sd = fmaf(s[c], ad_[c], sd); }
#pragma unroll
  for (int m = 1; m < 64; m <<= 1) { sa += __shfl_xor(sa, m, 64); sd += __shfl_xor(sd, m, 64); }
  if (lane == 0) { asf[b] = sa; adf[b] = sd; }
}

// ---------------- GAT attention softmax -> alphaf[dst][h*256+src] (f32) -------------
__global__ __launch_bounds__(256) void k_alpha(const float* asf, const float* adf,
    const float* maskv, float* alphaf) {
  int dd = blockIdx.x, s = threadIdx.x;
  int lane = s & 63, w = s >> 6;
  __shared__ float wr[2][4][4];
  float mk = maskv[dd * 256 + s];
  float lg[4];
#pragma unroll
  for (int h = 0; h < 4; ++h) {
    float v = adf[dd * 4 + h] + asf[s * 4 + h];
    lg[h] = lrelu(v) + mk;
  }
#pragma unroll
  for (int h = 0; h < 4; ++h) {
    float v = lg[h];
#pragma unroll
    for (int m = 1; m < 64; m <<= 1) v = fmaxf(v, __shfl_xor(v, m, 64));
    if (lane == 0) wr[0][h][w] = v;
  }
  __syncthreads();
  float e[4];
#pragma unroll
  for (int h = 0; h < 4; ++h) {
    float mx = fmaxf(fmaxf(wr[0][h][0], wr[0][h][1]), fmaxf(wr[0][h][2], wr[0][h][3]));
    float v = __expf(lg[h] - mx);
    e[h] = v;
#pragma unroll
    for (int m = 1; m < 64; m <<= 1) v += __shfl_xor(v, m, 64);
    if (lane == 0) wr[1][h][w] = v;
  }
  __syncthreads();
#pragma unroll
  for (int h = 0; h < 4; ++h) {
    float sm = wr[1][h][0] + wr[1][h][1] + wr[1][h][2] + wr[1][h][3];
    alphaf[dd * 1024 + h * 256 + s] = e[h] / sm;
  }
}

// ---------------- naive aggregation: x' = leaky(0.25*sum alpha*s + b) ---------------
__global__ __launch_bounds__(256) void k_agg(const float* alphaf, const float* sf,
    const float* vecf, int l, float* xout) {
  int c = blockIdx.x * 256 + threadIdx.x;   // grid.x = 2
  int i = blockIdx.y;
  float acc = 0.f;
#pragma unroll
  for (int h = 0; h < 4; ++h) {
    const float* al = alphaf + i * 1024 + h * 256;
    const float* sc = sf + h * 512 + c;
    for (int j = 0; j < 256; ++j)
      acc = fmaf(al[j], sc[j * 2048], acc);
  }
  float b = vecf[16016 + l * 512 + c];
  xout[i * 512 + c] = lrelu(fmaf(acc, 0.25f, b));
}

// ---------------- naive linear: out[i][c] = x[i] . W[:,c] + bias --------------------
__global__ __launch_bounds__(256) void k_op(const float* x, const float* Wf,
    const float* bias, float* out) {
  int c = blockIdx.x * 256 + threadIdx.x;   // grid.x = 2
  int i = blockIdx.y;
  const float* xr = x + i * 512;
  const float* w = Wf + c;
  float acc = 0.f;
  for (int k = 0; k < 512; ++k) acc = fmaf(xr[k], w[k * 512], acc);
  out[i * 512 + c] = acc + bias[c];
}

// ---------------- output-proj LayerNorm + leaky -> f32 ------------------------------
__global__ __launch_bounds__(256) void k_ln(const float* t1, const float* vecf, float* h1f) {
  const float* g_ = vecf + 18064;
  const float* be_ = vecf + 18576;
  int row = blockIdx.x, tid = threadIdx.x, lane = tid & 63, w = tid >> 6;
  __shared__ float wr[2][4];
  float v0 = t1[row * 512 + tid];
  float v1 = t1[row * 512 + 256 + tid];
  float s = v0 + v1, s2 = fmaf(v0, v0, v1 * v1);
#pragma unroll
  for (int m = 1; m < 64; m <<= 1) { s += __shfl_xor(s, m, 64); s2 += __shfl_xor(s2, m, 64); }
  if (lane == 0) { wr[0][w] = s; wr[1][w] = s2; }
  __syncthreads();
  s = wr[0][0] + wr[0][1] + wr[0][2] + wr[0][3];
  s2 = wr[1][0] + wr[1][1] + wr[1][2] + wr[1][3];
  float m = s * (1.f / 512.f);
  float var = fmaxf(s2 * (1.f / 512.f) - m * m, 0.f);
  float iv = 1.f / sqrtf(var + 1e-5f);
  float z0 = (v0 - m) * iv * g_[tid] + be_[tid];
  float z1 = (v1 - m) * iv * g_[tid + 256] + be_[tid + 256];
  h1f[row * 512 + tid] = lrelu(z0);
  h1f[row * 512 + 256 + tid] = lrelu(z1);
}

// ---------------- final linear -> f32 out -------------------------------------------
__global__ __launch_bounds__(256) void k_op2(const float* x, const float* Wf,
    const float* vecf, float* outf) {
  int c = blockIdx.x * 256 + threadIdx.x;   // grid.x = 2
  int i = blockIdx.y;
  const float* xr = x + i * 512;
  const float* w = Wf + c;
  float acc = 0.f;
  for (int k = 0; k < 512; ++k) acc = fmaf(xr[k], w[k * 512], acc);
  outf[i * 512 + c] = acc + vecf[19088 + c];
}

extern "C" void kernel_launch(void* const* d_in, const int* in_sizes, int n_in,
                              void* d_out, int out_size, void* d_ws, size_t ws_size,
                              hipStream_t stream) {
  (void)out_size;
  // Role order (setup_inputs dict): 0 emb, 1 ep_w1, 2 ep_b1, 3 ep_g, 4 ep_beta,
  // 5 ep_w2, 6 ep_b2, 7 ef_w1, 8 ef_b1, 9 ef_g, 10 ef_beta, 11 ef_w2, 12 ef_b2,
  // 13 gat_W, 14 a_src, 15 a_dst, 16 gat_b, 17 op_w1, 18 op_b1, 19 op_g,
  // 20 op_beta, 21 op_w2, 22 op_b2.
  static const int dictT[23] = {0,1,2,3,4,5,6,7,8,9,10,11,12,13,14,15,16,17,18,19,20,21,22};
  static const int alphaT[23] = {6,11,7,10,9,12,8,4,0,3,2,5,1,13,15,14,16,21,17,20,19,22,18};
  const int* tbl = (n_in == 23 && in_sizes[0] == 512) ? alphaT : dictT;
  auto IN = [&](int role) -> const void* { return d_in[tbl[role]]; };

  float* out_f = (float*)d_out;                    // [256,512] f32
  float* act_f = out_f + 256 * 512;                // [256,256] f32 0/1
  float* ef_f  = out_f + 256 * 512 + 256 * 256;    // [256,256,128] f32

  char* cur = (char*)d_ws;
  auto alloc = [&](size_t bytes) -> void* {
    void* r = (void*)cur;
    cur += (bytes + 255) & ~(size_t)255;
    return r;
  };
  float* vecf    = (float*)alloc(20480 * 4);
  float* embf    = (float*)alloc(131072 * 4);
  float* epw1f   = (float*)alloc(524288 * 4);
  float* efw1f   = (float*)alloc(524288 * 4);
  float* gatWf   = (float*)alloc(3145728 * 4);
  float* opw1f   = (float*)alloc(262144 * 4);
  float* opw2f   = (float*)alloc(262144 * 4);
  float* efw2f   = (float*)alloc(65536 * 4);
  float* uvf     = (float*)alloc(524288 * 4);
  float* sf      = (float*)alloc(524288 * 4);
  float* alphaf  = (float*)alloc(262144 * 4);
  float* asf     = (float*)alloc(1024 * 4);
  float* adf     = (float*)alloc(1024 * 4);
  float* xf      = (float*)alloc(262144 * 4);
  float* t1      = (float*)alloc(131072 * 4);
  float* h1f     = (float*)alloc(131072 * 4);
  float* maskv   = (float*)alloc(65536 * 4);
  double* sums   = (double*)alloc(1024 * 8);
  double* sumsq  = (double*)alloc(1024 * 8);
  double* crossef = (double*)alloc(65536 * 8);
  int* flag      = (int*)alloc(256);
  if ((size_t)(cur - (char*)d_ws) > ws_size) return;

  hipMemsetAsync(flag, 0, 256, stream);
  hipLaunchKernelGGL(k_detect, dim3(64), dim3(256), 0, stream, (const u16*)IN(0), flag);

  { // small vectors -> canonical f32
    VArgs va;
    auto setV = [&](int qi, int role, int dst, int n) { va.v[qi] = {IN(role), dst, n}; };
    setV(0, 2, 0, 512);       // ep_b1
    setV(1, 3, 512, 512);     // ep_g
    setV(2, 4, 1024, 512);    // ep_beta
    setV(3, 5, 1536, 512);    // ep_w2
    setV(4, 6, 2048, 1);      // ep_b2
    setV(5, 8, 2064, 512);    // ef_b1
    setV(6, 9, 2576, 512);    // ef_g
    setV(7, 10, 3088, 512);   // ef_beta
    setV(8, 12, 3600, 128);   // ef_b2
    setV(9, 14, 3728, 6144);  // gat_a_src
    setV(10, 15, 9872, 6144); // gat_a_dst
    setV(11, 16, 16016, 1536);// gat_b
    setV(12, 18, 17552, 512); // op_b1
    setV(13, 19, 18064, 512); // op_g
    setV(14, 20, 18576, 512); // op_beta
    setV(15, 22, 19088, 512); // op_b2
    hipLaunchKernelGGL(k_vec, dim3(16), dim3(256), 0, stream, va, (const int*)flag, vecf);
  }

  { // big matrices -> canonical f32
    CArgs ca;
    ca.src[0] = IN(0);  ca.dst[0] = embf;  ca.n[0] = 131072;
    ca.src[1] = IN(1);  ca.dst[1] = epw1f; ca.n[1] = 524288;
    ca.src[2] = IN(7);  ca.dst[2] = efw1f; ca.n[2] = 524288;
    ca.src[3] = IN(13); ca.dst[3] = gatWf; ca.n[3] = 3145728;
    ca.src[4] = IN(17); ca.dst[4] = opw1f; ca.n[4] = 262144;
    ca.src[5] = IN(21); ca.dst[5] = opw2f; ca.n[5] = 262144;
    ca.src[6] = IN(11); ca.dst[6] = efw2f; ca.n[6] = 65536;
    hipLaunchKernelGGL(k_cvt, dim3(2048, 7), dim3(256), 0, stream, ca, (const int*)flag);
  }

  hipLaunchKernelGGL(k_uv, dim3(2048), dim3(256), 0, stream, embf, epw1f, efw1f, vecf, uvf);
  hipLaunchKernelGGL(k_stats64, dim3(1024), dim3(64), 0, stream, uvf, sums, sumsq);
  hipLaunchKernelGGL(k_cross, dim3(16, 16), dim3(256), 0, stream, uvf, crossef);

  hipLaunchKernelGGL(k_ep_lit, dim3(16384), dim3(256), 0, stream, uvf, vecf, act_f, maskv);
  hipLaunchKernelGGL(k_efn, dim3(2048), dim3(256), 0, stream,
                     uvf, sums, sumsq, crossef, vecf, efw2f, ef_f);

  const float* xsrc = embf;
  for (int l = 0; l < 3; ++l) {
    hipLaunchKernelGGL(k_s, dim3(8, 256), dim3(256), 0, stream,
                       xsrc, gatWf + l * 1048576, sf);
    hipLaunchKernelGGL(k_ad, dim3(1024), dim3(64), 0, stream, sf, vecf, l, asf, adf);
    hipLaunchKernelGGL(k_alpha, dim3(256), dim3(256), 0, stream, asf, adf, maskv, alphaf);
    float* xdst = xf + (l & 1) * 131072;
    hipLaunchKernelGGL(k_agg, dim3(2, 256), dim3(256), 0, stream, alphaf, sf, vecf, l, xdst);
    xsrc = xdst;
  }

  hipLaunchKernelGGL(k_op, dim3(2, 256), dim3(256), 0, stream, xsrc, opw1f, vecf + 17552, t1);
  hipLaunchKernelGGL(k_ln, dim3(256), dim3(256), 0, stream, t1, vecf, h1f);
  hipLaunchKernelGGL(k_op2, dim3(2, 256), dim3(256), 0, stream, h1f, opw2f, vecf, out_f);
}

// Round 7
// 582.308 us; speedup vs baseline: 1.1543x; 1.1543x over previous
//
#include <hip/hip_runtime.h>

// NeuralAudioGraph: N=256, D=H=512, E=128, 4 heads, 3 GAT layers.
// r7: green baseline (672 us) -> optimize. k_efn (150us, MfmaUtil=0, VALU 56%)
// replaced by fused bf16-MFMA k_ef (f32 out; ef threshold ~8*eps*454 ~ 28 >> bf16
// error ~0.5). k_s/k_agg re-tiled to amortize L2 reads 4x (stay f32: softmax
// logit sensitivity). Edge predictor stays literal f64 (hard prob>0.5 threshold).

typedef __attribute__((ext_vector_type(8))) short short8;   // 8 x bf16 (MFMA frag)
typedef __attribute__((ext_vector_type(4))) float f32x4;    // MFMA accumulator
typedef unsigned short u16;
typedef unsigned int u32;

__device__ __forceinline__ float bf2f(u16 h) { return __uint_as_float(((u32)h) << 16); }
__device__ __forceinline__ u16 f2bf(float f) {
  u32 u = __float_as_uint(f);
  u += 0x7fffu + ((u >> 16) & 1u);   // round-to-nearest-even
  return (u16)(u >> 16);
}
__device__ __forceinline__ float lrelu(float v) { return fmaxf(v, 0.2f * v); }
__device__ __forceinline__ float ldany(int f32mode, const void* p, int i) {
  return f32mode ? ((const float*)p)[i] : bf2f(((const u16*)p)[i]);
}

// ---------------- dtype detector: f32 bits read as bf16 contain huge values --------
__global__ __launch_bounds__(256) void k_detect(const u16* emb, int* flag) {
  bool big = false;
  for (int i = blockIdx.x * 256 + threadIdx.x; i < 131072; i += 256 * 64) {
    float v = bf2f(emb[i]);
    big |= !(fabsf(v) <= 1e6f);
  }
  unsigned long long m = __ballot(big);
  if (m && (threadIdx.x & 63) == 0) atomicOr(flag, 1);
}

// ---------------- small-vector ingest -> canonical f32 ------------------------------
struct VD { const void* src; int dst, n; };
struct VArgs { VD v[16]; };
__global__ __launch_bounds__(256) void k_vec(VArgs a, const int* flag, float* out) {
  int f = *flag;
  VD d = a.v[blockIdx.x];
  for (int i = threadIdx.x; i < d.n; i += 256)
    out[d.dst + i] = ldany(f, d.src, i);
}

// ---------------- big-matrix ingest -> canonical f32 --------------------------------
struct CArgs { const void* src[7]; float* dst[7]; int n[7]; };
__global__ __launch_bounds__(256) void k_cvt(CArgs a, const int* flag) {
  int f = *flag;
  int e = blockIdx.y;
  const void* s = a.src[e];
  float* d = a.dst[e];
  int n = a.n[e];
  for (int i = blockIdx.x * 256 + threadIdx.x; i < n; i += 2048 * 256)
    d[i] = ldany(f, s, i);
}

// ---------------- ef_w2 f32 [512][128] -> bf16 transpose [128][512] -----------------
__global__ __launch_bounds__(256) void k_w2tb(const float* efw2f, u16* w2tb) {
  int idx = blockIdx.x * 256 + threadIdx.x;   // 65536
  int n = idx >> 9, c = idx & 511;
  w2tb[idx] = f2bf(efw2f[c * 128 + n]);
}

// ---------------- U/V = emb @ W1 halves, f64 accumulate, f32 out --------------------
// arr 0: U_ep, 1: V_ep(+ep_b1), 2: U_ef, 3: V_ef(+ef_b1)
__global__ __launch_bounds__(256) void k_uv(const float* embf, const float* epw1f,
    const float* efw1f, const float* vecf, float* uvf) {
  int idx = blockIdx.x * 256 + threadIdx.x;   // 524288
  int col = idx & 511;
  int row = (idx >> 9) & 255;
  int arr = idx >> 17;
  const float* W = (arr < 2) ? epw1f : efw1f;
  const float* e = embf + row * 512;
  const float* w = W + (arr & 1) * 512 * 512 + col;
  double acc = 0.0;
  for (int c = 0; c < 512; ++c)
    acc += (double)e[c] * (double)w[c * 512];
  float bias = (arr == 1) ? vecf[col] : (arr == 3) ? vecf[2064 + col] : 0.f;
  uvf[idx] = (float)(acc + (double)bias);
}

// ---------------- f64 row sums / sums-of-squares (feeds k_ef) -----------------------
__global__ __launch_bounds__(64) void k_stats64(const float* uvf, double* sums, double* sumsq) {
  int bid = blockIdx.x;           // arr*256 + row
  int lane = threadIdx.x;
  const float* p = uvf + bid * 512;
  double s = 0.0, s2 = 0.0;
  for (int q = lane; q < 512; q += 64) { double v = p[q]; s += v; s2 += v * v; }
#pragma unroll
  for (int m = 1; m < 64; m <<= 1) { s += __shfl_xor(s, m, 64); s2 += __shfl_xor(s2, m, 64); }
  if (lane == 0) { sums[bid] = s; sumsq[bid] = s2; }
}

// ---------------- cross[i][j] = U_i . V_j (f64) for the ef LN variance --------------
__global__ __launch_bounds__(256) void k_cross(const float* uvf, double* crossef) {
  __shared__ float Uc[16][132], Vc[16][132];
  const float* U = uvf + 262144;
  const float* V = U + 131072;
  int tid = threadIdx.x, ti = tid & 15, tj = tid >> 4;
  int i0 = blockIdx.y * 16, j0 = blockIdx.x * 16;
  double acc = 0.0;
  for (int c0 = 0; c0 < 512; c0 += 128) {
    __syncthreads();
    for (int idx = tid; idx < 2048; idx += 256) {
      int r = idx >> 7, c = idx & 127;
      Uc[r][c] = U[(i0 + r) * 512 + c0 + c];
      Vc[r][c] = V[(j0 + r) * 512 + c0 + c];
    }
    __syncthreads();
    for (int c = 0; c < 128; ++c)
      acc += (double)Uc[ti][c] * (double)Vc[tj][c];
  }
  crossef[(i0 + ti) * 256 + j0 + tj] = acc;
}

// ---------------- LITERAL edge predictor: one wave per pair -------------------------
__global__ __launch_bounds__(256) void k_ep_lit(const float* uvf, const float* vecf,
                                                float* act, float* maskv) {
  int lane = threadIdx.x & 63, w = threadIdx.x >> 6;
  int pair = blockIdx.x * 4 + w;           // grid 16384
  int i = pair >> 8, j = pair & 255;
  const float* Up = uvf + i * 512 + lane * 8;
  const float* Vp = uvf + 131072 + j * 512 + lane * 8;
  float4 u0 = *(const float4*)Up, u1 = *(const float4*)(Up + 4);
  float4 v0 = *(const float4*)Vp, v1 = *(const float4*)(Vp + 4);
  float h[8] = {u0.x + v0.x, u0.y + v0.y, u0.z + v0.z, u0.w + v0.w,
                u1.x + v1.x, u1.y + v1.y, u1.z + v1.z, u1.w + v1.w};
  double s = 0.0;
#pragma unroll
  for (int k = 0; k < 8; ++k) s += (double)h[k];
#pragma unroll
  for (int m = 1; m < 64; m <<= 1) s += __shfl_xor(s, m, 64);
  float mean = (float)(s * (1.0 / 512.0));
  double q = 0.0;
#pragma unroll
  for (int k = 0; k < 8; ++k) { double dd = (double)(h[k] - mean); q += dd * dd; }
#pragma unroll
  for (int m = 1; m < 64; m <<= 1) q += __shfl_xor(q, m, 64);
  float iv = (float)(1.0 / sqrt(q * (1.0 / 512.0) + 1e-5));
  const float* g_ = vecf + 512 + lane * 8;
  const float* be_ = vecf + 1024 + lane * 8;
  const float* w2_ = vecf + 1536 + lane * 8;
  double acc = 0.0;
#pragma unroll
  for (int k = 0; k < 8; ++k) {
    float z = (h[k] - mean) * iv * g_[k] + be_[k];
    acc += (double)(lrelu(z) * w2_[k]);
  }
#pragma unroll
  for (int m = 1; m < 64; m <<= 1) acc += __shfl_xor(acc, m, 64);
  if (lane == 0) {
    double logit = acc + (double)vecf[2048];
    bool a = (logit > 0.0) && (i != j);
    act[i * 256 + j] = a ? 1.0f : 0.0f;
    maskv[j * 256 + i] = (a || i == j) ? 0.f : -1e9f;         // adj[dst][src] mask
  }
}

// ---------------- edge features: fused h-compute + bf16 MFMA, f32 out ---------------
// 512 blocks: 4 i x 32 j = 128 pairs x 128 outputs, K=512 in 8 chunks of 64.
__global__ __launch_bounds__(256) void k_ef(const float* uvf, const double* sums,
    const double* sumsq, const double* crossef, const float* vecf,
    const u16* w2tb, float* ef_f) {
  __shared__ u16 hS[128 * 72];
  __shared__ u16 wS[128 * 72];
  __shared__ float bI[128], ivI[128];
  const float* g_ = vecf + 2576;
  const float* be_ = vecf + 3088;
  int tid = threadIdx.x;
  int lane = tid & 63, w = tid >> 6;
  int bx = blockIdx.x;
  int i0 = (bx >> 3) * 4, j0 = (bx & 7) * 32;
  const float* U = uvf + 262144;
  const float* V = uvf + 393216;
  if (tid < 128) {
    int i = i0 + (tid >> 5), j = j0 + (tid & 31);
    double m = (sums[512 + i] + sums[768 + j]) * (1.0 / 512.0);
    double q = (sumsq[512 + i] + 2.0 * crossef[i * 256 + j] + sumsq[768 + j]) * (1.0 / 512.0);
    float iv = (float)(1.0 / sqrt(q - m * m + 1e-5));
    ivI[tid] = iv;
    bI[tid] = (float)(-m) * iv;
  }
  f32x4 acc[2][8];
#pragma unroll
  for (int ai = 0; ai < 2; ++ai)
#pragma unroll
    for (int bi = 0; bi < 8; ++bi) acc[ai][bi] = (f32x4){0.f, 0.f, 0.f, 0.f};
  __syncthreads();

  int p = tid >> 1, co = (tid & 1) * 32;
  const float* Up = U + (i0 + (p >> 5)) * 512 + co;
  const float* Vp = V + (j0 + (p & 31)) * 512 + co;

  for (int kc = 0; kc < 8; ++kc) {
    int c0 = kc * 64;
    if (kc) __syncthreads();
    { // stage ef_w2^T chunk: wS[n][k_local] = w2tb[n*512 + c0+co + k]
      const u16* src = w2tb + p * 512 + c0 + co;
      u16* dst = wS + p * 72 + co;
#pragma unroll
      for (int qq = 0; qq < 4; ++qq)
        *(short8*)(dst + qq * 8) = *(const short8*)(src + qq * 8);
    }
    { // h = leaky(LN(U+V)*g+beta), 32 channels of pair p, bf16 into LDS
      float iv = ivI[p], bb = bI[p];
      u16* hp = hS + p * 72 + co;
#pragma unroll
      for (int c = 0; c < 32; c += 4) {
        float4 uu = *(const float4*)(Up + c0 + c);
        float4 vv = *(const float4*)(Vp + c0 + c);
        float4 g4 = *(const float4*)(g_ + c0 + co + c);
        float4 b4 = *(const float4*)(be_ + c0 + co + c);
        ushort4 hv;
        float z;
        z = fmaf(uu.x + vv.x, iv, bb); z = fmaf(z, g4.x, b4.x); hv.x = f2bf(lrelu(z));
        z = fmaf(uu.y + vv.y, iv, bb); z = fmaf(z, g4.y, b4.y); hv.y = f2bf(lrelu(z));
        z = fmaf(uu.z + vv.z, iv, bb); z = fmaf(z, g4.z, b4.z); hv.z = f2bf(lrelu(z));
        z = fmaf(uu.w + vv.w, iv, bb); z = fmaf(z, g4.w, b4.w); hv.w = f2bf(lrelu(z));
        *(ushort4*)(hp + c) = hv;
      }
    }
    __syncthreads();
#pragma unroll
    for (int ks = 0; ks < 2; ++ks) {
      int kk = ks * 32 + (lane >> 4) * 8;
      short8 a0 = *(const short8*)(hS + (w * 32 + (lane & 15)) * 72 + kk);
      short8 a1 = *(const short8*)(hS + (w * 32 + 16 + (lane & 15)) * 72 + kk);
#pragma unroll
      for (int nt = 0; nt < 8; ++nt) {
        short8 bv = *(const short8*)(wS + (nt * 16 + (lane & 15)) * 72 + kk);
        acc[0][nt] = __builtin_amdgcn_mfma_f32_16x16x32_bf16(a0, bv, acc[0][nt], 0, 0, 0);
        acc[1][nt] = __builtin_amdgcn_mfma_f32_16x16x32_bf16(a1, bv, acc[1][nt], 0, 0, 0);
      }
    }
  }
#pragma unroll
  for (int mi = 0; mi < 2; ++mi) {
    int pb = w * 32 + mi * 16 + (lane >> 4) * 4;
#pragma unroll
    for (int nt = 0; nt < 8; ++nt) {
      int n = nt * 16 + (lane & 15);
      float bias = vecf[3600 + n];
#pragma unroll
      for (int r = 0; r < 4; ++r) {
        int pp = pb + r;
        int pair = (i0 + (pp >> 5)) * 256 + j0 + (pp & 31);
        ef_f[pair * 128 + n] = acc[mi][nt][r] + bias;
      }
    }
  }
}

// ---------------- GAT s = x @ W[l], f32, 4 n-rows per block (LDS-staged x) ----------
__global__ __launch_bounds__(256) void k_s(const float* x, const float* Wf, float* sf) {
  __shared__ float xS[4 * 512];
  int tid = threadIdx.x;
  int hc = blockIdx.x * 256 + tid;           // grid.x = 8
  int n0 = blockIdx.y * 4;                   // grid.y = 64
#pragma unroll
  for (int q = 0; q < 8; ++q) {
    int idx = q * 256 + tid;
    xS[idx] = x[n0 * 512 + idx];
  }
  __syncthreads();
  float acc0 = 0.f, acc1 = 0.f, acc2 = 0.f, acc3 = 0.f;
  for (int c = 0; c < 512; ++c) {
    float wv = Wf[c * 2048 + hc];
    acc0 = fmaf(xS[c], wv, acc0);
    acc1 = fmaf(xS[512 + c], wv, acc1);
    acc2 = fmaf(xS[1024 + c], wv, acc2);
    acc3 = fmaf(xS[1536 + c], wv, acc3);
  }
  sf[(n0 + 0) * 2048 + hc] = acc0;
  sf[(n0 + 1) * 2048 + hc] = acc1;
  sf[(n0 + 2) * 2048 + hc] = acc2;
  sf[(n0 + 3) * 2048 + hc] = acc3;
}

// ---------------- naive a_src/a_dst dots (block per (n,h)) --------------------------
__global__ __launch_bounds__(64) void k_ad(const float* sf, const float* vecf, int l,
                                           float* asf, float* adf) {
  int b = blockIdx.x;            // n*4+h
  int n = b >> 2, h = b & 3;
  int lane = threadIdx.x;
  const float* s = sf + n * 2048 + h * 512;
  const float* as_ = vecf + 3728 + l * 2048 + h * 512;
  const float* ad_ = vecf + 9872 + l * 2048 + h * 512;
  float sa = 0.f, sd = 0.f;
  for (int c = lane; c < 512; c += 64) { sa = fmaf(s[c], as_[c], sa); sd = fmaf(s[c], ad_[c], sd); }
#pragma unroll
  for (int m = 1; m < 64; m <<= 1) { sa += __shfl_xor(sa, m, 64); sd += __shfl_xor(sd, m, 64); }
  if (lane == 0) { asf[b] = sa; adf[b] = sd; }
}

// ---------------- GAT attention softmax -> alphaf[dst][h*256+src] (f32) -------------
__global__ __launch_bounds__(256) void k_alpha(const float* asf, const float* adf,
    const float* maskv, float* alphaf) {
  int dd = blockIdx.x, s = threadIdx.x;
  int lane = s & 63, w = s >> 6;
  __shared__ float wr[2][4][4];
  float mk = maskv[dd * 256 + s];
  float lg[4];
#pragma unroll
  for (int h = 0; h < 4; ++h) {
    float v = adf[dd * 4 + h] + asf[s * 4 + h];
    lg[h] = lrelu(v) + mk;
  }
#pragma unroll
  for (int h = 0; h < 4; ++h) {
    float v = lg[h];
#pragma unroll
    for (int m = 1; m < 64; m <<= 1) v = fmaxf(v, __shfl_xor(v, m, 64));
    if (lane == 0) wr[0][h][w] = v;
  }
  __syncthreads();
  float e[4];
#pragma unroll
  for (int h = 0; h < 4; ++h) {
    float mx = fmaxf(fmaxf(wr[0][h][0], wr[0][h][1]), fmaxf(wr[0][h][2], wr[0][h][3]));
    float v = __expf(lg[h] - mx);
    e[h] = v;
#pragma unroll
    for (int m = 1; m < 64; m <<= 1) v += __shfl_xor(v, m, 64);
    if (lane == 0) wr[1][h][w] = v;
  }
  __syncthreads();
#pragma unroll
  for (int h = 0; h < 4; ++h) {
    float sm = wr[1][h][0] + wr[1][h][1] + wr[1][h][2] + wr[1][h][3];
    alphaf[dd * 1024 + h * 256 + s] = e[h] / sm;
  }
}

// ---------------- aggregation: x' = leaky(0.25*sum alpha*s + b), 4 i per block ------
__global__ __launch_bounds__(256) void k_agg(const float* alphaf, const float* sf,
    const float* vecf, int l, float* xout) {
  __shared__ float aS[4 * 1024];
  int tid = threadIdx.x;
  int c = blockIdx.x * 256 + tid;            // grid.x = 2
  int i0 = blockIdx.y * 4;                   // grid.y = 64
#pragma unroll
  for (int q = 0; q < 16; ++q) {
    int idx = q * 256 + tid;
    aS[idx] = alphaf[(i0 + (idx >> 10)) * 1024 + (idx & 1023)];
  }
  __syncthreads();
  float a0 = 0.f, a1 = 0.f, a2 = 0.f, a3 = 0.f;
#pragma unroll
  for (int h = 0; h < 4; ++h) {
    const float* sc = sf + h * 512 + c;
    const float* al = aS + h * 256;
    for (int j = 0; j < 256; ++j) {
      float sv = sc[j * 2048];
      a0 = fmaf(al[j], sv, a0);
      a1 = fmaf(al[1024 + j], sv, a1);
      a2 = fmaf(al[2048 + j], sv, a2);
      a3 = fmaf(al[3072 + j], sv, a3);
    }
  }
  float b = vecf[16016 + l * 512 + c];
  xout[(i0 + 0) * 512 + c] = lrelu(fmaf(a0, 0.25f, b));
  xout[(i0 + 1) * 512 + c] = lrelu(fmaf(a1, 0.25f, b));
  xout[(i0 + 2) * 512 + c] = lrelu(fmaf(a2, 0.25f, b));
  xout[(i0 + 3) * 512 + c] = lrelu(fmaf(a3, 0.25f, b));
}

// ---------------- naive linear: out[i][c] = x[i] . W[:,c] + bias --------------------
__global__ __launch_bounds__(256) void k_op(const float* x, const float* Wf,
    const float* bias, float* out) {
  int c = blockIdx.x * 256 + threadIdx.x;   // grid.x = 2
  int i = blockIdx.y;
  const float* xr = x + i * 512;
  const float* w = Wf + c;
  float acc = 0.f;
  for (int k = 0; k < 512; ++k) acc = fmaf(xr[k], w[k * 512], acc);
  out[i * 512 + c] = acc + bias[c];
}

// ---------------- output-proj LayerNorm + leaky -> f32 ------------------------------
__global__ __launch_bounds__(256) void k_ln(const float* t1, const float* vecf, float* h1f) {
  const float* g_ = vecf + 18064;
  const float* be_ = vecf + 18576;
  int row = blockIdx.x, tid = threadIdx.x, lane = tid & 63, w = tid >> 6;
  __shared__ float wr[2][4];
  float v0 = t1[row * 512 + tid];
  float v1 = t1[row * 512 + 256 + tid];
  float s = v0 + v1, s2 = fmaf(v0, v0, v1 * v1);
#pragma unroll
  for (int m = 1; m < 64; m <<= 1) { s += __shfl_xor(s, m, 64); s2 += __shfl_xor(s2, m, 64); }
  if (lane == 0) { wr[0][w] = s; wr[1][w] = s2; }
  __syncthreads();
  s = wr[0][0] + wr[0][1] + wr[0][2] + wr[0][3];
  s2 = wr[1][0] + wr[1][1] + wr[1][2] + wr[1][3];
  float m = s * (1.f / 512.f);
  float var = fmaxf(s2 * (1.f / 512.f) - m * m, 0.f);
  float iv = 1.f / sqrtf(var + 1e-5f);
  float z0 = (v0 - m) * iv * g_[tid] + be_[tid];
  float z1 = (v1 - m) * iv * g_[tid + 256] + be_[tid + 256];
  h1f[row * 512 + tid] = lrelu(z0);
  h1f[row * 512 + 256 + tid] = lrelu(z1);
}

// ---------------- final linear -> f32 out -------------------------------------------
__global__ __launch_bounds__(256) void k_op2(const float* x, const float* Wf,
    const float* vecf, float* outf) {
  int c = blockIdx.x * 256 + threadIdx.x;   // grid.x = 2
  int i = blockIdx.y;
  const float* xr = x + i * 512;
  const float* w = Wf + c;
  float acc = 0.f;
  for (int k = 0; k < 512; ++k) acc = fmaf(xr[k], w[k * 512], acc);
  outf[i * 512 + c] = acc + vecf[19088 + c];
}

extern "C" void kernel_launch(void* const* d_in, const int* in_sizes, int n_in,
                              void* d_out, int out_size, void* d_ws, size_t ws_size,
                              hipStream_t stream) {
  (void)out_size;
  static const int dictT[23] = {0,1,2,3,4,5,6,7,8,9,10,11,12,13,14,15,16,17,18,19,20,21,22};
  static const int alphaT[23] = {6,11,7,10,9,12,8,4,0,3,2,5,1,13,15,14,16,21,17,20,19,22,18};
  const int* tbl = (n_in == 23 && in_sizes[0] == 512) ? alphaT : dictT;
  auto IN = [&](int role) -> const void* { return d_in[tbl[role]]; };

  float* out_f = (float*)d_out;                    // [256,512] f32
  float* act_f = out_f + 256 * 512;                // [256,256] f32 0/1
  float* ef_f  = out_f + 256 * 512 + 256 * 256;    // [256,256,128] f32

  char* cur = (char*)d_ws;
  auto alloc = [&](size_t bytes) -> void* {
    void* r = (void*)cur;
    cur += (bytes + 255) & ~(size_t)255;
    return r;
  };
  float* vecf    = (float*)alloc(20480 * 4);
  float* embf    = (float*)alloc(131072 * 4);
  float* epw1f   = (float*)alloc(524288 * 4);
  float* efw1f   = (float*)alloc(524288 * 4);
  float* gatWf   = (float*)alloc(3145728 * 4);
  float* opw1f   = (float*)alloc(262144 * 4);
  float* opw2f   = (float*)alloc(262144 * 4);
  float* efw2f   = (float*)alloc(65536 * 4);
  float* uvf     = (float*)alloc(524288 * 4);
  float* sf      = (float*)alloc(524288 * 4);
  float* alphaf  = (float*)alloc(262144 * 4);
  float* asf     = (float*)alloc(1024 * 4);
  float* adf     = (float*)alloc(1024 * 4);
  float* xf      = (float*)alloc(262144 * 4);
  float* t1      = (float*)alloc(131072 * 4);
  float* h1f     = (float*)alloc(131072 * 4);
  float* maskv   = (float*)alloc(65536 * 4);
  double* sums   = (double*)alloc(1024 * 8);
  double* sumsq  = (double*)alloc(1024 * 8);
  double* crossef = (double*)alloc(65536 * 8);
  u16* w2tb      = (u16*)alloc(65536 * 2);
  int* flag      = (int*)alloc(256);
  if ((size_t)(cur - (char*)d_ws) > ws_size) return;

  hipMemsetAsync(flag, 0, 256, stream);
  hipLaunchKernelGGL(k_detect, dim3(64), dim3(256), 0, stream, (const u16*)IN(0), flag);

  { // small vectors -> canonical f32
    VArgs va;
    auto setV = [&](int qi, int role, int dst, int n) { va.v[qi] = {IN(role), dst, n}; };
    setV(0, 2, 0, 512);       // ep_b1
    setV(1, 3, 512, 512);     // ep_g
    setV(2, 4, 1024, 512);    // ep_beta
    setV(3, 5, 1536, 512);    // ep_w2
    setV(4, 6, 2048, 1);      // ep_b2
    setV(5, 8, 2064, 512);    // ef_b1
    setV(6, 9, 2576, 512);    // ef_g
    setV(7, 10, 3088, 512);   // ef_beta
    setV(8, 12, 3600, 128);   // ef_b2
    setV(9, 14, 3728, 6144);  // gat_a_src
    setV(10, 15, 9872, 6144); // gat_a_dst
    setV(11, 16, 16016, 1536);// gat_b
    setV(12, 18, 17552, 512); // op_b1
    setV(13, 19, 18064, 512); // op_g
    setV(14, 20, 18576, 512); // op_beta
    setV(15, 22, 19088, 512); // op_b2
    hipLaunchKernelGGL(k_vec, dim3(16), dim3(256), 0, stream, va, (const int*)flag, vecf);
  }

  { // big matrices -> canonical f32
    CArgs ca;
    ca.src[0] = IN(0);  ca.dst[0] = embf;  ca.n[0] = 131072;
    ca.src[1] = IN(1);  ca.dst[1] = epw1f; ca.n[1] = 524288;
    ca.src[2] = IN(7);  ca.dst[2] = efw1f; ca.n[2] = 524288;
    ca.src[3] = IN(13); ca.dst[3] = gatWf; ca.n[3] = 3145728;
    ca.src[4] = IN(17); ca.dst[4] = opw1f; ca.n[4] = 262144;
    ca.src[5] = IN(21); ca.dst[5] = opw2f; ca.n[5] = 262144;
    ca.src[6] = IN(11); ca.dst[6] = efw2f; ca.n[6] = 65536;
    hipLaunchKernelGGL(k_cvt, dim3(2048, 7), dim3(256), 0, stream, ca, (const int*)flag);
  }
  hipLaunchKernelGGL(k_w2tb, dim3(256), dim3(256), 0, stream, efw2f, w2tb);

  hipLaunchKernelGGL(k_uv, dim3(2048), dim3(256), 0, stream, embf, epw1f, efw1f, vecf, uvf);
  hipLaunchKernelGGL(k_stats64, dim3(1024), dim3(64), 0, stream, uvf, sums, sumsq);
  hipLaunchKernelGGL(k_cross, dim3(16, 16), dim3(256), 0, stream, uvf, crossef);

  hipLaunchKernelGGL(k_ep_lit, dim3(16384), dim3(256), 0, stream, uvf, vecf, act_f, maskv);
  hipLaunchKernelGGL(k_ef, dim3(512), dim3(256), 0, stream,
                     uvf, sums, sumsq, crossef, vecf, w2tb, ef_f);

  const float* xsrc = embf;
  for (int l = 0; l < 3; ++l) {
    hipLaunchKernelGGL(k_s, dim3(8, 64), dim3(256), 0, stream,
                       xsrc, gatWf + l * 1048576, sf);
    hipLaunchKernelGGL(k_ad, dim3(1024), dim3(64), 0, stream, sf, vecf, l, asf, adf);
    hipLaunchKernelGGL(k_alpha, dim3(256), dim3(256), 0, stream, asf, adf, maskv, alphaf);
    float* xdst = xf + (l & 1) * 131072;
    hipLaunchKernelGGL(k_agg, dim3(2, 64), dim3(256), 0, stream, alphaf, sf, vecf, l, xdst);
    xsrc = xdst;
  }

  hipLaunchKernelGGL(k_op, dim3(2, 256), dim3(256), 0, stream, xsrc, opw1f, vecf + 17552, t1);
  hipLaunchKernelGGL(k_ln, dim3(256), dim3(256), 0, stream, t1, vecf, h1f);
  hipLaunchKernelGGL(k_op2, dim3(2, 256), dim3(256), 0, stream, h1f, opw2f, vecf, out_f);
}

// Round 8
// 563.767 us; speedup vs baseline: 1.1923x; 1.0329x over previous
//
#include <hip/hip_runtime.h>

// NeuralAudioGraph: N=256, D=H=512, E=128, 4 heads, 3 GAT layers.
// r8: k_uv register-blocked (f64 only for ep arrays; f32 for ef), k_ep_lit ->
// stats-based tiled k_ep_t (f64 stats identical to validated k_ef), k_cross
// vectorized + computes both crossep/crossef, k_s/k_op/k_op2 row-blocked with
// wave-uniform scalar x loads. MFMA k_ef validated in r7 (absmax unchanged).

typedef __attribute__((ext_vector_type(8))) short short8;   // 8 x bf16 (MFMA frag)
typedef __attribute__((ext_vector_type(4))) float f32x4;    // MFMA accumulator
typedef unsigned short u16;
typedef unsigned int u32;

__device__ __forceinline__ float bf2f(u16 h) { return __uint_as_float(((u32)h) << 16); }
__device__ __forceinline__ u16 f2bf(float f) {
  u32 u = __float_as_uint(f);
  u += 0x7fffu + ((u >> 16) & 1u);   // round-to-nearest-even
  return (u16)(u >> 16);
}
__device__ __forceinline__ float lrelu(float v) { return fmaxf(v, 0.2f * v); }
__device__ __forceinline__ float ldany(int f32mode, const void* p, int i) {
  return f32mode ? ((const float*)p)[i] : bf2f(((const u16*)p)[i]);
}

// ---------------- dtype detector ----------------------------------------------------
__global__ __launch_bounds__(256) void k_detect(const u16* emb, int* flag) {
  bool big = false;
  for (int i = blockIdx.x * 256 + threadIdx.x; i < 131072; i += 256 * 64) {
    float v = bf2f(emb[i]);
    big |= !(fabsf(v) <= 1e6f);
  }
  unsigned long long m = __ballot(big);
  if (m && (threadIdx.x & 63) == 0) atomicOr(flag, 1);
}

// ---------------- small-vector ingest -> canonical f32 ------------------------------
struct VD { const void* src; int dst, n; };
struct VArgs { VD v[16]; };
__global__ __launch_bounds__(256) void k_vec(VArgs a, const int* flag, float* out) {
  int f = *flag;
  VD d = a.v[blockIdx.x];
  for (int i = threadIdx.x; i < d.n; i += 256)
    out[d.dst + i] = ldany(f, d.src, i);
}

// ---------------- big-matrix ingest -> canonical f32 --------------------------------
struct CArgs { const void* src[7]; float* dst[7]; int n[7]; };
__global__ __launch_bounds__(256) void k_cvt(CArgs a, const int* flag) {
  int f = *flag;
  int e = blockIdx.y;
  const void* s = a.src[e];
  float* d = a.dst[e];
  int n = a.n[e];
  for (int i = blockIdx.x * 256 + threadIdx.x; i < n; i += 2048 * 256)
    d[i] = ldany(f, s, i);
}

// ---------------- ef_w2 f32 [512][128] -> bf16 transpose [128][512] -----------------
__global__ __launch_bounds__(256) void k_w2tb(const float* efw2f, u16* w2tb) {
  int idx = blockIdx.x * 256 + threadIdx.x;   // 65536
  int n = idx >> 9, c = idx & 511;
  w2tb[idx] = f2bf(efw2f[c * 128 + n]);
}

// ---------------- U/V = emb @ W1 halves; f64 for ep (arr 0,1), f32 for ef -----------
// grid (2, 64, 4): x = col half, y = 4-row group, z = arr.
__global__ __launch_bounds__(256) void k_uv(const float* embf, const float* epw1f,
    const float* efw1f, const float* vecf, float* uvf) {
  int tid = threadIdx.x;
  int col = blockIdx.x * 256 + tid;
  int r0 = blockIdx.y * 4;
  int arr = blockIdx.z;
  const float* W = ((arr < 2) ? epw1f : efw1f) + (arr & 1) * 262144 + col;
  const float* e = embf + r0 * 512;
  float bias = (arr == 1) ? vecf[col] : (arr == 3) ? vecf[2064 + col] : 0.f;
  float* outp = uvf + arr * 131072 + r0 * 512 + col;
  if (arr < 2) {
    double a0 = 0.0, a1 = 0.0, a2 = 0.0, a3 = 0.0;
    for (int k = 0; k < 512; k += 2) {
      double w0 = (double)W[k * 512];
      double w1 = (double)W[(k + 1) * 512];
      float2 e0 = *(const float2*)(e + k);
      float2 e1 = *(const float2*)(e + 512 + k);
      float2 e2 = *(const float2*)(e + 1024 + k);
      float2 e3 = *(const float2*)(e + 1536 + k);
      a0 += (double)e0.x * w0 + (double)e0.y * w1;
      a1 += (double)e1.x * w0 + (double)e1.y * w1;
      a2 += (double)e2.x * w0 + (double)e2.y * w1;
      a3 += (double)e3.x * w0 + (double)e3.y * w1;
    }
    outp[0]    = (float)(a0 + (double)bias);
    outp[512]  = (float)(a1 + (double)bias);
    outp[1024] = (float)(a2 + (double)bias);
    outp[1536] = (float)(a3 + (double)bias);
  } else {
    float a0 = 0.f, a1 = 0.f, a2 = 0.f, a3 = 0.f;
    for (int k = 0; k < 512; k += 2) {
      float w0 = W[k * 512], w1 = W[(k + 1) * 512];
      float2 e0 = *(const float2*)(e + k);
      float2 e1 = *(const float2*)(e + 512 + k);
      float2 e2 = *(const float2*)(e + 1024 + k);
      float2 e3 = *(const float2*)(e + 1536 + k);
      a0 = fmaf(e0.x, w0, fmaf(e0.y, w1, a0));
      a1 = fmaf(e1.x, w0, fmaf(e1.y, w1, a1));
      a2 = fmaf(e2.x, w0, fmaf(e2.y, w1, a2));
      a3 = fmaf(e3.x, w0, fmaf(e3.y, w1, a3));
    }
    outp[0]    = a0 + bias;
    outp[512]  = a1 + bias;
    outp[1024] = a2 + bias;
    outp[1536] = a3 + bias;
  }
}

// ---------------- f64 row sums / sums-of-squares ------------------------------------
__global__ __launch_bounds__(64) void k_stats64(const float* uvf, double* sums, double* sumsq) {
  int bid = blockIdx.x;           // arr*256 + row
  int lane = threadIdx.x;
  const float* p = uvf + bid * 512;
  double s = 0.0, s2 = 0.0;
  for (int q = lane; q < 512; q += 64) { double v = p[q]; s += v; s2 += v * v; }
#pragma unroll
  for (int m = 1; m < 64; m <<= 1) { s += __shfl_xor(s, m, 64); s2 += __shfl_xor(s2, m, 64); }
  if (lane == 0) { sums[bid] = s; sumsq[bid] = s2; }
}

// ---------------- cross[i][j] = U_i . V_j (f64): z=0 -> ep, z=1 -> ef ---------------
__global__ __launch_bounds__(256) void k_cross(const float* uvf, double* crossep,
                                               double* crossef) {
  __shared__ float Uc[16][132], Vc[16][132];
  int z = blockIdx.z;
  const float* U = uvf + z * 262144;
  const float* V = U + 131072;
  double* out = z ? crossef : crossep;
  int tid = threadIdx.x, ti = tid & 15, tj = tid >> 4;
  int i0 = blockIdx.y * 16, j0 = blockIdx.x * 16;
  double acc = 0.0;
  for (int c0 = 0; c0 < 512; c0 += 128) {
    __syncthreads();
    for (int idx = tid; idx < 2048; idx += 256) {
      int r = idx >> 7, c = idx & 127;
      Uc[r][c] = U[(i0 + r) * 512 + c0 + c];
      Vc[r][c] = V[(j0 + r) * 512 + c0 + c];
    }
    __syncthreads();
#pragma unroll
    for (int c4 = 0; c4 < 128; c4 += 4) {
      float4 uu = *(const float4*)&Uc[ti][c4];
      float4 vv = *(const float4*)&Vc[tj][c4];
      float p = fmaf(uu.x, vv.x, fmaf(uu.y, vv.y, fmaf(uu.z, vv.z, uu.w * vv.w)));
      acc += (double)p;
    }
  }
  out[(i0 + ti) * 256 + j0 + tj] = acc;
}

// ---------------- edge predictor, stats-based tiled (1 thread / pair) ---------------
// LN stats from f64 sums/sumsq/crossep (same math as validated k_ef); f64-grouped dot.
__global__ __launch_bounds__(256) void k_ep_t(const float* uvf, const double* sums,
    const double* sumsq, const double* crossep, const float* vecf,
    float* act, float* maskv) {
  __shared__ float Uc[16][132], Vc[16][132];
  int tid = threadIdx.x, ti = tid & 15, tj = tid >> 4;
  int i0 = blockIdx.y * 16, j0 = blockIdx.x * 16;
  int i = i0 + ti, j = j0 + tj;
  double md = (sums[i] + sums[256 + j]) * (1.0 / 512.0);
  double qd = (sumsq[i] + 2.0 * crossep[i * 256 + j] + sumsq[256 + j]) * (1.0 / 512.0);
  float iv = (float)(1.0 / sqrt(qd - md * md + 1e-5));
  float bb = (float)(-md) * iv;
  const float* U = uvf;
  const float* V = uvf + 131072;
  const float* g_ = vecf + 512;
  const float* be_ = vecf + 1024;
  const float* w2_ = vecf + 1536;
  double acc = 0.0;
  for (int c0 = 0; c0 < 512; c0 += 128) {
    __syncthreads();
    for (int idx = tid; idx < 2048; idx += 256) {
      int r = idx >> 7, c = idx & 127;
      Uc[r][c] = U[(i0 + r) * 512 + c0 + c];
      Vc[r][c] = V[(j0 + r) * 512 + c0 + c];
    }
    __syncthreads();
#pragma unroll
    for (int c4 = 0; c4 < 128; c4 += 4) {
      float4 uu = *(const float4*)&Uc[ti][c4];
      float4 vv = *(const float4*)&Vc[tj][c4];
      float4 gg = *(const float4*)(g_ + c0 + c4);
      float4 b4 = *(const float4*)(be_ + c0 + c4);
      float4 w4 = *(const float4*)(w2_ + c0 + c4);
      float z, s4 = 0.f;
      z = fmaf(fmaf(uu.x + vv.x, iv, bb), gg.x, b4.x); s4 = fmaf(lrelu(z), w4.x, s4);
      z = fmaf(fmaf(uu.y + vv.y, iv, bb), gg.y, b4.y); s4 = fmaf(lrelu(z), w4.y, s4);
      z = fmaf(fmaf(uu.z + vv.z, iv, bb), gg.z, b4.z); s4 = fmaf(lrelu(z), w4.z, s4);
      z = fmaf(fmaf(uu.w + vv.w, iv, bb), gg.w, b4.w); s4 = fmaf(lrelu(z), w4.w, s4);
      acc += (double)s4;
    }
  }
  double logit = acc + (double)vecf[2048];
  bool a = (logit > 0.0) && (i != j);
  act[i * 256 + j] = a ? 1.0f : 0.0f;
  maskv[j * 256 + i] = (a || i == j) ? 0.f : -1e9f;         // adj[dst][src] mask
}

// ---------------- edge features: fused h-compute + bf16 MFMA, f32 out ---------------
__global__ __launch_bounds__(256) void k_ef(const float* uvf, const double* sums,
    const double* sumsq, const double* crossef, const float* vecf,
    const u16* w2tb, float* ef_f) {
  __shared__ u16 hS[128 * 72];
  __shared__ u16 wS[128 * 72];
  __shared__ float bI[128], ivI[128];
  const float* g_ = vecf + 2576;
  const float* be_ = vecf + 3088;
  int tid = threadIdx.x;
  int lane = tid & 63, w = tid >> 6;
  int bx = blockIdx.x;
  int i0 = (bx >> 3) * 4, j0 = (bx & 7) * 32;
  const float* U = uvf + 262144;
  const float* V = uvf + 393216;
  if (tid < 128) {
    int i = i0 + (tid >> 5), j = j0 + (tid & 31);
    double m = (sums[512 + i] + sums[768 + j]) * (1.0 / 512.0);
    double q = (sumsq[512 + i] + 2.0 * crossef[i * 256 + j] + sumsq[768 + j]) * (1.0 / 512.0);
    float iv = (float)(1.0 / sqrt(q - m * m + 1e-5));
    ivI[tid] = iv;
    bI[tid] = (float)(-m) * iv;
  }
  f32x4 acc[2][8];
#pragma unroll
  for (int ai = 0; ai < 2; ++ai)
#pragma unroll
    for (int bi = 0; bi < 8; ++bi) acc[ai][bi] = (f32x4){0.f, 0.f, 0.f, 0.f};
  __syncthreads();

  int p = tid >> 1, co = (tid & 1) * 32;
  const float* Up = U + (i0 + (p >> 5)) * 512 + co;
  const float* Vp = V + (j0 + (p & 31)) * 512 + co;

  for (int kc = 0; kc < 8; ++kc) {
    int c0 = kc * 64;
    if (kc) __syncthreads();
    {
      const u16* src = w2tb + p * 512 + c0 + co;
      u16* dst = wS + p * 72 + co;
#pragma unroll
      for (int qq = 0; qq < 4; ++qq)
        *(short8*)(dst + qq * 8) = *(const short8*)(src + qq * 8);
    }
    {
      float iv = ivI[p], bb = bI[p];
      u16* hp = hS + p * 72 + co;
#pragma unroll
      for (int c = 0; c < 32; c += 4) {
        float4 uu = *(const float4*)(Up + c0 + c);
        float4 vv = *(const float4*)(Vp + c0 + c);
        float4 g4 = *(const float4*)(g_ + c0 + co + c);
        float4 b4 = *(const float4*)(be_ + c0 + co + c);
        ushort4 hv;
        float z;
        z = fmaf(uu.x + vv.x, iv, bb); z = fmaf(z, g4.x, b4.x); hv.x = f2bf(lrelu(z));
        z = fmaf(uu.y + vv.y, iv, bb); z = fmaf(z, g4.y, b4.y); hv.y = f2bf(lrelu(z));
        z = fmaf(uu.z + vv.z, iv, bb); z = fmaf(z, g4.z, b4.z); hv.z = f2bf(lrelu(z));
        z = fmaf(uu.w + vv.w, iv, bb); z = fmaf(z, g4.w, b4.w); hv.w = f2bf(lrelu(z));
        *(ushort4*)(hp + c) = hv;
      }
    }
    __syncthreads();
#pragma unroll
    for (int ks = 0; ks < 2; ++ks) {
      int kk = ks * 32 + (lane >> 4) * 8;
      short8 a0 = *(const short8*)(hS + (w * 32 + (lane & 15)) * 72 + kk);
      short8 a1 = *(const short8*)(hS + (w * 32 + 16 + (lane & 15)) * 72 + kk);
#pragma unroll
      for (int nt = 0; nt < 8; ++nt) {
        short8 bv = *(const short8*)(wS + (nt * 16 + (lane & 15)) * 72 + kk);
        acc[0][nt] = __builtin_amdgcn_mfma_f32_16x16x32_bf16(a0, bv, acc[0][nt], 0, 0, 0);
        acc[1][nt] = __builtin_amdgcn_mfma_f32_16x16x32_bf16(a1, bv, acc[1][nt], 0, 0, 0);
      }
    }
  }
#pragma unroll
  for (int mi = 0; mi < 2; ++mi) {
    int pb = w * 32 + mi * 16 + (lane >> 4) * 4;
#pragma unroll
    for (int nt = 0; nt < 8; ++nt) {
      int n = nt * 16 + (lane & 15);
      float bias = vecf[3600 + n];
#pragma unroll
      for (int r = 0; r < 4; ++r) {
        int pp = pb + r;
        int pair = (i0 + (pp >> 5)) * 256 + j0 + (pp & 31);
        ef_f[pair * 128 + n] = acc[mi][nt][r] + bias;
      }
    }
  }
}

// ---------------- GAT s = x @ W[l]; 4 rows/thread, uniform x via s_load -------------
__global__ __launch_bounds__(256) void k_s(const float* x, const float* Wf, float* sf) {
  int tid = threadIdx.x;
  int hc = blockIdx.x * 256 + tid;           // grid.x = 8
  int n0 = blockIdx.y * 4;                   // grid.y = 64
  const float* xr = x + n0 * 512;
  float a0 = 0.f, a1 = 0.f, a2 = 0.f, a3 = 0.f;
  for (int k = 0; k < 512; k += 2) {
    float w0 = Wf[k * 2048 + hc], w1 = Wf[(k + 1) * 2048 + hc];
    float2 x0 = *(const float2*)(xr + k);
    float2 x1 = *(const float2*)(xr + 512 + k);
    float2 x2 = *(const float2*)(xr + 1024 + k);
    float2 x3 = *(const float2*)(xr + 1536 + k);
    a0 = fmaf(x0.x, w0, fmaf(x0.y, w1, a0));
    a1 = fmaf(x1.x, w0, fmaf(x1.y, w1, a1));
    a2 = fmaf(x2.x, w0, fmaf(x2.y, w1, a2));
    a3 = fmaf(x3.x, w0, fmaf(x3.y, w1, a3));
  }
  sf[(n0 + 0) * 2048 + hc] = a0;
  sf[(n0 + 1) * 2048 + hc] = a1;
  sf[(n0 + 2) * 2048 + hc] = a2;
  sf[(n0 + 3) * 2048 + hc] = a3;
}

// ---------------- naive a_src/a_dst dots (block per (n,h)) --------------------------
__global__ __launch_bounds__(64) void k_ad(const float* sf, const float* vecf, int l,
                                           float* asf, float* adf) {
  int b = blockIdx.x;            // n*4+h
  int n = b >> 2, h = b & 3;
  int lane = threadIdx.x;
  const float* s = sf + n * 2048 + h * 512;
  const float* as_ = vecf + 3728 + l * 2048 + h * 512;
  const float* ad_ = vecf + 9872 + l * 2048 + h * 512;
  float sa = 0.f, sd = 0.f;
  for (int c = lane; c < 512; c += 64) { sa = fmaf(s[c], as_[c], sa); sd = fmaf(s[c], ad_[c], sd); }
#pragma unroll
  for (int m = 1; m < 64; m <<= 1) { sa += __shfl_xor(sa, m, 64); sd += __shfl_xor(sd, m, 64); }
  if (lane == 0) { asf[b] = sa; adf[b] = sd; }
}

// ---------------- GAT attention softmax -> alphaf[dst][h*256+src] (f32) -------------
__global__ __launch_bounds__(256) void k_alpha(const float* asf, const float* adf,
    const float* maskv, float* alphaf) {
  int dd = blockIdx.x, s = threadIdx.x;
  int lane = s & 63, w = s >> 6;
  __shared__ float wr[2][4][4];
  float mk = maskv[dd * 256 + s];
  float lg[4];
#pragma unroll
  for (int h = 0; h < 4; ++h) {
    float v = adf[dd * 4 + h] + asf[s * 4 + h];
    lg[h] = lrelu(v) + mk;
  }
#pragma unroll
  for (int h = 0; h < 4; ++h) {
    float v = lg[h];
#pragma unroll
    for (int m = 1; m < 64; m <<= 1) v = fmaxf(v, __shfl_xor(v, m, 64));
    if (lane == 0) wr[0][h][w] = v;
  }
  __syncthreads();
  float e[4];
#pragma unroll
  for (int h = 0; h < 4; ++h) {
    float mx = fmaxf(fmaxf(wr[0][h][0], wr[0][h][1]), fmaxf(wr[0][h][2], wr[0][h][3]));
    float v = __expf(lg[h] - mx);
    e[h] = v;
#pragma unroll
    for (int m = 1; m < 64; m <<= 1) v += __shfl_xor(v, m, 64);
    if (lane == 0) wr[1][h][w] = v;
  }
  __syncthreads();
#pragma unroll
  for (int h = 0; h < 4; ++h) {
    float sm = wr[1][h][0] + wr[1][h][1] + wr[1][h][2] + wr[1][h][3];
    alphaf[dd * 1024 + h * 256 + s] = e[h] / sm;
  }
}

// ---------------- aggregation: x' = leaky(0.25*sum alpha*s + b), 4 i per block ------
__global__ __launch_bounds__(256) void k_agg(const float* alphaf, const float* sf,
    const float* vecf, int l, float* xout) {
  __shared__ float aS[4 * 1024];
  int tid = threadIdx.x;
  int c = blockIdx.x * 256 + tid;            // grid.x = 2
  int i0 = blockIdx.y * 4;                   // grid.y = 64
#pragma unroll
  for (int q = 0; q < 16; ++q) {
    int idx = q * 256 + tid;
    aS[idx] = alphaf[(i0 + (idx >> 10)) * 1024 + (idx & 1023)];
  }
  __syncthreads();
  float a0 = 0.f, a1 = 0.f, a2 = 0.f, a3 = 0.f;
#pragma unroll
  for (int h = 0; h < 4; ++h) {
    const float* sc = sf + h * 512 + c;
    const float* al = aS + h * 256;
    for (int j = 0; j < 256; ++j) {
      float sv = sc[j * 2048];
      a0 = fmaf(al[j], sv, a0);
      a1 = fmaf(al[1024 + j], sv, a1);
      a2 = fmaf(al[2048 + j], sv, a2);
      a3 = fmaf(al[3072 + j], sv, a3);
    }
  }
  float b = vecf[16016 + l * 512 + c];
  xout[(i0 + 0) * 512 + c] = lrelu(fmaf(a0, 0.25f, b));
  xout[(i0 + 1) * 512 + c] = lrelu(fmaf(a1, 0.25f, b));
  xout[(i0 + 2) * 512 + c] = lrelu(fmaf(a2, 0.25f, b));
  xout[(i0 + 3) * 512 + c] = lrelu(fmaf(a3, 0.25f, b));
}

// ---------------- linear: out[i][c] = x[i].W[:,c] + bias; 2 rows/thread -------------
__global__ __launch_bounds__(256) void k_op(const float* x, const float* Wf,
    const float* bias, float* out) {
  int tid = threadIdx.x;
  int c = blockIdx.x * 256 + tid;            // grid.x = 2
  int i0 = blockIdx.y * 2;                   // grid.y = 128
  const float* xr = x + i0 * 512;
  float a0 = 0.f, a1 = 0.f;
  for (int k = 0; k < 512; k += 2) {
    float w0 = Wf[k * 512 + c], w1 = Wf[(k + 1) * 512 + c];
    float2 x0 = *(const float2*)(xr + k);
    float2 x1 = *(const float2*)(xr + 512 + k);
    a0 = fmaf(x0.x, w0, fmaf(x0.y, w1, a0));
    a1 = fmaf(x1.x, w0, fmaf(x1.y, w1, a1));
  }
  out[(i0 + 0) * 512 + c] = a0 + bias[c];
  out[(i0 + 1) * 512 + c] = a1 + bias[c];
}

// ---------------- output-proj LayerNorm + leaky -> f32 ------------------------------
__global__ __launch_bounds__(256) void k_ln(const float* t1, const float* vecf, float* h1f) {
  const float* g_ = vecf + 18064;
  const float* be_ = vecf + 18576;
  int row = blockIdx.x, tid = threadIdx.x, lane = tid & 63, w = tid >> 6;
  __shared__ float wr[2][4];
  float v0 = t1[row * 512 + tid];
  float v1 = t1[row * 512 + 256 + tid];
  float s = v0 + v1, s2 = fmaf(v0, v0, v1 * v1);
#pragma unroll
  for (int m = 1; m < 64; m <<= 1) { s += __shfl_xor(s, m, 64); s2 += __shfl_xor(s2, m, 64); }
  if (lane == 0) { wr[0][w] = s; wr[1][w] = s2; }
  __syncthreads();
  s = wr[0][0] + wr[0][1] + wr[0][2] + wr[0][3];
  s2 = wr[1][0] + wr[1][1] + wr[1][2] + wr[1][3];
  float m = s * (1.f / 512.f);
  float var = fmaxf(s2 * (1.f / 512.f) - m * m, 0.f);
  float iv = 1.f / sqrtf(var + 1e-5f);
  float z0 = (v0 - m) * iv * g_[tid] + be_[tid];
  float z1 = (v1 - m) * iv * g_[tid + 256] + be_[tid + 256];
  h1f[row * 512 + tid] = lrelu(z0);
  h1f[row * 512 + 256 + tid] = lrelu(z1);
}

// ---------------- final linear -> f32 out; 2 rows/thread ----------------------------
__global__ __launch_bounds__(256) void k_op2(const float* x, const float* Wf,
    const float* vecf, float* outf) {
  int tid = threadIdx.x;
  int c = blockIdx.x * 256 + tid;            // grid.x = 2
  int i0 = blockIdx.y * 2;                   // grid.y = 128
  const float* xr = x + i0 * 512;
  float a0 = 0.f, a1 = 0.f;
  for (int k = 0; k < 512; k += 2) {
    float w0 = Wf[k * 512 + c], w1 = Wf[(k + 1) * 512 + c];
    float2 x0 = *(const float2*)(xr + k);
    float2 x1 = *(const float2*)(xr + 512 + k);
    a0 = fmaf(x0.x, w0, fmaf(x0.y, w1, a0));
    a1 = fmaf(x1.x, w0, fmaf(x1.y, w1, a1));
  }
  outf[(i0 + 0) * 512 + c] = a0 + vecf[19088 + c];
  outf[(i0 + 1) * 512 + c] = a1 + vecf[19088 + c];
}

extern "C" void kernel_launch(void* const* d_in, const int* in_sizes, int n_in,
                              void* d_out, int out_size, void* d_ws, size_t ws_size,
                              hipStream_t stream) {
  (void)out_size;
  static const int dictT[23] = {0,1,2,3,4,5,6,7,8,9,10,11,12,13,14,15,16,17,18,19,20,21,22};
  static const int alphaT[23] = {6,11,7,10,9,12,8,4,0,3,2,5,1,13,15,14,16,21,17,20,19,22,18};
  const int* tbl = (n_in == 23 && in_sizes[0] == 512) ? alphaT : dictT;
  auto IN = [&](int role) -> const void* { return d_in[tbl[role]]; };

  float* out_f = (float*)d_out;                    // [256,512] f32
  float* act_f = out_f + 256 * 512;                // [256,256] f32 0/1
  float* ef_f  = out_f + 256 * 512 + 256 * 256;    // [256,256,128] f32

  char* cur = (char*)d_ws;
  auto alloc = [&](size_t bytes) -> void* {
    void* r = (void*)cur;
    cur += (bytes + 255) & ~(size_t)255;
    return r;
  };
  float* vecf    = (float*)alloc(20480 * 4);
  float* embf    = (float*)alloc(131072 * 4);
  float* epw1f   = (float*)alloc(524288 * 4);
  float* efw1f   = (float*)alloc(524288 * 4);
  float* gatWf   = (float*)alloc(3145728 * 4);
  float* opw1f   = (float*)alloc(262144 * 4);
  float* opw2f   = (float*)alloc(262144 * 4);
  float* efw2f   = (float*)alloc(65536 * 4);
  float* uvf     = (float*)alloc(524288 * 4);
  float* sf      = (float*)alloc(524288 * 4);
  float* alphaf  = (float*)alloc(262144 * 4);
  float* asf     = (float*)alloc(1024 * 4);
  float* adf     = (float*)alloc(1024 * 4);
  float* xf      = (float*)alloc(262144 * 4);
  float* t1      = (float*)alloc(131072 * 4);
  float* h1f     = (float*)alloc(131072 * 4);
  float* maskv   = (float*)alloc(65536 * 4);
  double* sums   = (double*)alloc(1024 * 8);
  double* sumsq  = (double*)alloc(1024 * 8);
  double* crossep = (double*)alloc(65536 * 8);
  double* crossef = (double*)alloc(65536 * 8);
  u16* w2tb      = (u16*)alloc(65536 * 2);
  int* flag      = (int*)alloc(256);
  if ((size_t)(cur - (char*)d_ws) > ws_size) return;

  hipMemsetAsync(flag, 0, 256, stream);
  hipLaunchKernelGGL(k_detect, dim3(64), dim3(256), 0, stream, (const u16*)IN(0), flag);

  { // small vectors -> canonical f32
    VArgs va;
    auto setV = [&](int qi, int role, int dst, int n) { va.v[qi] = {IN(role), dst, n}; };
    setV(0, 2, 0, 512);       // ep_b1
    setV(1, 3, 512, 512);     // ep_g
    setV(2, 4, 1024, 512);    // ep_beta
    setV(3, 5, 1536, 512);    // ep_w2
    setV(4, 6, 2048, 1);      // ep_b2
    setV(5, 8, 2064, 512);    // ef_b1
    setV(6, 9, 2576, 512);    // ef_g
    setV(7, 10, 3088, 512);   // ef_beta
    setV(8, 12, 3600, 128);   // ef_b2
    setV(9, 14, 3728, 6144);  // gat_a_src
    setV(10, 15, 9872, 6144); // gat_a_dst
    setV(11, 16, 16016, 1536);// gat_b
    setV(12, 18, 17552, 512); // op_b1
    setV(13, 19, 18064, 512); // op_g
    setV(14, 20, 18576, 512); // op_beta
    setV(15, 22, 19088, 512); // op_b2
    hipLaunchKernelGGL(k_vec, dim3(16), dim3(256), 0, stream, va, (const int*)flag, vecf);
  }

  { // big matrices -> canonical f32
    CArgs ca;
    ca.src[0] = IN(0);  ca.dst[0] = embf;  ca.n[0] = 131072;
    ca.src[1] = IN(1);  ca.dst[1] = epw1f; ca.n[1] = 524288;
    ca.src[2] = IN(7);  ca.dst[2] = efw1f; ca.n[2] = 524288;
    ca.src[3] = IN(13); ca.dst[3] = gatWf; ca.n[3] = 3145728;
    ca.src[4] = IN(17); ca.dst[4] = opw1f; ca.n[4] = 262144;
    ca.src[5] = IN(21); ca.dst[5] = opw2f; ca.n[5] = 262144;
    ca.src[6] = IN(11); ca.dst[6] = efw2f; ca.n[6] = 65536;
    hipLaunchKernelGGL(k_cvt, dim3(2048, 7), dim3(256), 0, stream, ca, (const int*)flag);
  }
  hipLaunchKernelGGL(k_w2tb, dim3(256), dim3(256), 0, stream, efw2f, w2tb);

  hipLaunchKernelGGL(k_uv, dim3(2, 64, 4), dim3(256), 0, stream, embf, epw1f, efw1f, vecf, uvf);
  hipLaunchKernelGGL(k_stats64, dim3(1024), dim3(64), 0, stream, uvf, sums, sumsq);
  hipLaunchKernelGGL(k_cross, dim3(16, 16, 2), dim3(256), 0, stream, uvf, crossep, crossef);

  hipLaunchKernelGGL(k_ep_t, dim3(16, 16), dim3(256), 0, stream,
                     uvf, sums, sumsq, crossep, vecf, act_f, maskv);
  hipLaunchKernelGGL(k_ef, dim3(512), dim3(256), 0, stream,
                     uvf, sums, sumsq, crossef, vecf, w2tb, ef_f);

  const float* xsrc = embf;
  for (int l = 0; l < 3; ++l) {
    hipLaunchKernelGGL(k_s, dim3(8, 64), dim3(256), 0, stream,
                       xsrc, gatWf + l * 1048576, sf);
    hipLaunchKernelGGL(k_ad, dim3(1024), dim3(64), 0, stream, sf, vecf, l, asf, adf);
    hipLaunchKernelGGL(k_alpha, dim3(256), dim3(256), 0, stream, asf, adf, maskv, alphaf);
    float* xdst = xf + (l & 1) * 131072;
    hipLaunchKernelGGL(k_agg, dim3(2, 64), dim3(256), 0, stream, alphaf, sf, vecf, l, xdst);
    xsrc = xdst;
  }

  hipLaunchKernelGGL(k_op, dim3(2, 128), dim3(256), 0, stream, xsrc, opw1f, vecf + 17552, t1);
  hipLaunchKernelGGL(k_ln, dim3(256), dim3(256), 0, stream, t1, vecf, h1f);
  hipLaunchKernelGGL(k_op2, dim3(2, 128), dim3(256), 0, stream, h1f, opw2f, vecf, out_f);
}